// Round 3
// baseline (286.990 us; speedup 1.0000x reference)
//
#include <hip/hip_runtime.h>
#include <hip/hip_fp16.h>
#include <cstdint>

// ---------- types ----------
typedef unsigned short ushort_t;
typedef _Float16 f16x8 __attribute__((ext_vector_type(8)));  // 8 f16 (4 VGPRs) for MFMA
typedef float f32x4 __attribute__((ext_vector_type(4)));

#define B_SZ   64
#define U_SZ   512
#define M_TOT  32768      // B*U
#define N_TOT  1024       // HID
#define K_EMB  256        // unit embedding features (first 256 of concat)
#define K_CORE 512        // core features (last 512 of concat)
#define ACT    12

__device__ __forceinline__ unsigned int pack2h(float a, float b) {
    __half2 h = __floats2half2_rn(a, b);   // RNE f32->f16 pair
    union { __half2 h2; unsigned int u; } v; v.h2 = h; return v.u;
}

// ---------- kernel 1: transpose+convert W1[0:256, 0:1024] f32 -> W1T f16 [1024][256] ----------
__global__ __launch_bounds__(256) void transpose_k(const float* __restrict__ W1,
                                                   ushort_t* __restrict__ W1T) {
    __shared__ float tile[64][65];
    const int t = threadIdx.x;
    const int k0 = blockIdx.x * 64, n0 = blockIdx.y * 64;
    const int r = t >> 4, c4 = (t & 15) * 4;
#pragma unroll
    for (int p = 0; p < 4; ++p) {
        const int row = r + p * 16;   // k within tile
        const float4 v = *(const float4*)(W1 + (size_t)(k0 + row) * 1024 + n0 + c4);
        tile[row][c4 + 0] = v.x;
        tile[row][c4 + 1] = v.y;
        tile[row][c4 + 2] = v.z;
        tile[row][c4 + 3] = v.w;
    }
    __syncthreads();
#pragma unroll
    for (int p = 0; p < 4; ++p) {
        const int nrow = r + p * 16;  // n within tile
        uint2 o;
        o.x = pack2h(tile[c4 + 0][nrow], tile[c4 + 1][nrow]);
        o.y = pack2h(tile[c4 + 2][nrow], tile[c4 + 3][nrow]);
        *(uint2*)(W1T + (size_t)(n0 + nrow) * 256 + k0 + c4) = o;
    }
}

// ---------- kernel 2: cp[b][n] = b1[n] + sum_k core[b][k] * W1[256+k][n]  (pure f32, exact) ----------
__global__ __launch_bounds__(256) void corepart_k(const float* __restrict__ core,
                                                  const float* __restrict__ W1,
                                                  const float* __restrict__ b1,
                                                  float* __restrict__ cp) {
    const int b = blockIdx.y;
    const int n = blockIdx.x * 256 + threadIdx.x;
    float s = b1[n];
    const float* cr = core + b * K_CORE;
    const float* wp = W1 + (size_t)K_EMB * 1024 + n;
#pragma unroll 8
    for (int k = 0; k < K_CORE; ++k)
        s += cr[k] * wp[(size_t)k * 1024];
    cp[b * 1024 + n] = s;
}

// ---------- kernel 3: h = relu(emb @ W1[0:256] + cp[b]) -> out1 f32 [32768][1024] ----------
// 128x128 tile, BK=32, MFMA 16x16x32 f16, 4 waves in 2x2, register-prefetch staging.
// A side: f32 global -> convert f16 -> LDS. B side: f16 (w1t) straight copy.
__global__ __launch_bounds__(256) void gemm1_k(const float* __restrict__ emb,
                                               const ushort_t* __restrict__ w1t,
                                               const float* __restrict__ cp,
                                               float* __restrict__ out1) {
    __shared__ ushort_t Asl[128 * 32];
    __shared__ ushort_t Bsl[128 * 32];
    const int t = threadIdx.x;
    const int w = t >> 6, L = t & 63;
    const int wm = w >> 1, wn = w & 1;
    const int lane16 = L & 15, qd = L >> 4;
    const int n0 = blockIdx.x * 128, m0 = blockIdx.y * 128;
    const int bb = m0 >> 9;   // batch index (block never crosses a batch: 128 | 512)

    // staging: 512 chunks of 8 elems; thread covers chunks c0 and c0+64
    const int c0 = w * 128 + L, c1 = c0 + 64;
    const int rA0 = c0 >> 2, co0 = (c0 & 3) * 8;
    const int rA1 = c1 >> 2, co1 = (c1 & 3) * 8;
    const float* gA0 = emb + (size_t)(m0 + rA0) * K_EMB + co0;
    const float* gA1 = emb + (size_t)(m0 + rA1) * K_EMB + co1;
    const ushort_t* gB0 = w1t + (size_t)(n0 + rA0) * K_EMB + co0;
    const ushort_t* gB1 = w1t + (size_t)(n0 + rA1) * K_EMB + co1;
    uint4* lA0 = (uint4*)&Asl[c0 * 8];
    uint4* lA1 = (uint4*)&Asl[c1 * 8];
    uint4* lB0 = (uint4*)&Bsl[c0 * 8];
    uint4* lB1 = (uint4*)&Bsl[c1 * 8];

    float4 pa0l = *(const float4*)gA0, pa0h = *(const float4*)(gA0 + 4);
    float4 pa1l = *(const float4*)gA1, pa1h = *(const float4*)(gA1 + 4);
    uint4  pb0  = *(const uint4*)gB0,  pb1  = *(const uint4*)gB1;

    f32x4 acc[4][4];
#pragma unroll
    for (int mi = 0; mi < 4; ++mi)
#pragma unroll
        for (int ni = 0; ni < 4; ++ni)
            acc[mi][ni] = (f32x4){0.f, 0.f, 0.f, 0.f};

    for (int ks = 0; ks < 8; ++ks) {
        if (ks) __syncthreads();
        uint4 av0, av1;
        av0.x = pack2h(pa0l.x, pa0l.y); av0.y = pack2h(pa0l.z, pa0l.w);
        av0.z = pack2h(pa0h.x, pa0h.y); av0.w = pack2h(pa0h.z, pa0h.w);
        av1.x = pack2h(pa1l.x, pa1l.y); av1.y = pack2h(pa1l.z, pa1l.w);
        av1.z = pack2h(pa1h.x, pa1h.y); av1.w = pack2h(pa1h.z, pa1h.w);
        *lA0 = av0; *lA1 = av1; *lB0 = pb0; *lB1 = pb1;
        __syncthreads();
        if (ks < 7) {
            const int kk = (ks + 1) * 32;
            pa0l = *(const float4*)(gA0 + kk); pa0h = *(const float4*)(gA0 + kk + 4);
            pa1l = *(const float4*)(gA1 + kk); pa1h = *(const float4*)(gA1 + kk + 4);
            pb0 = *(const uint4*)(gB0 + kk);   pb1 = *(const uint4*)(gB1 + kk);
        }
        f16x8 af[4], bfr[4];
#pragma unroll
        for (int mi = 0; mi < 4; ++mi)
            af[mi] = *(const f16x8*)&Asl[(wm * 64 + mi * 16 + lane16) * 32 + qd * 8];
#pragma unroll
        for (int ni = 0; ni < 4; ++ni)
            bfr[ni] = *(const f16x8*)&Bsl[(wn * 64 + ni * 16 + lane16) * 32 + qd * 8];
#pragma unroll
        for (int mi = 0; mi < 4; ++mi)
#pragma unroll
            for (int ni = 0; ni < 4; ++ni)
                acc[mi][ni] = __builtin_amdgcn_mfma_f32_16x16x32_f16(af[mi], bfr[ni], acc[mi][ni], 0, 0, 0);
    }

    // epilogue: + cp[b][n], relu, store f32
    float cpv[4];
#pragma unroll
    for (int ni = 0; ni < 4; ++ni)
        cpv[ni] = cp[bb * 1024 + n0 + wn * 64 + ni * 16 + lane16];
#pragma unroll
    for (int mi = 0; mi < 4; ++mi) {
#pragma unroll
        for (int r = 0; r < 4; ++r) {
            const int m = m0 + wm * 64 + mi * 16 + qd * 4 + r;
            float* orow = out1 + (size_t)m * 1024 + n0 + wn * 64 + lane16;
#pragma unroll
            for (int ni = 0; ni < 4; ++ni) {
                const float v = acc[mi][ni][r] + cpv[ni];
                orow[ni * 16] = v > 0.f ? v : 0.f;
            }
        }
    }
}

// ---------- kernel 4: logits = h @ W2 + b2, softmax(12), range mask -> out0 f32 ----------
// 64 rows/block; thread (p = t>>5, q = t&31) covers rows {q*2, q*2+1}, k-range [p*128, p*128+128)
__global__ __launch_bounds__(256) void head_k(const float* __restrict__ h,
                                              const float* __restrict__ W2,
                                              const float* __restrict__ b2,
                                              const int* __restrict__ nr_units,
                                              const int* __restrict__ nr_flags,
                                              float* __restrict__ out0) {
    __shared__ float w2s[1024 * ACT];           // 48 KB
    __shared__ float red[4][32][2][ACT];        // 12 KB
    const int t = threadIdx.x;
    for (int i = t; i < 1024 * ACT; i += 256) w2s[i] = W2[i];
    __syncthreads();

    const int m0 = blockIdx.x * 64;
    const int p = t >> 5, q = t & 31;
    const int L = t & 63, w = t >> 6;
    const int kbase = p * 128;

    float part[2][ACT];
#pragma unroll
    for (int rr = 0; rr < 2; ++rr)
#pragma unroll
        for (int a = 0; a < ACT; ++a) part[rr][a] = 0.f;

    for (int j = 0; j < 16; ++j) {
        const int kb = kbase + j * 8;
        const float4* r0 = (const float4*)(h + (size_t)(m0 + q * 2 + 0) * 1024 + kb);
        const float4* r1 = (const float4*)(h + (size_t)(m0 + q * 2 + 1) * 1024 + kb);
        const float4 h0a = r0[0], h0b = r0[1];
        const float4 h1a = r1[0], h1b = r1[1];
        const float hv0[8] = {h0a.x, h0a.y, h0a.z, h0a.w, h0b.x, h0b.y, h0b.z, h0b.w};
        const float hv1[8] = {h1a.x, h1a.y, h1a.z, h1a.w, h1b.x, h1b.y, h1b.z, h1b.w};
#pragma unroll
        for (int e = 0; e < 8; ++e) {
            const f32x4* wr4 = (const f32x4*)&w2s[(kb + e) * ACT];
            const f32x4 w0 = wr4[0], w1 = wr4[1], w2v = wr4[2];
            const float h0 = hv0[e], h1 = hv1[e];
#pragma unroll
            for (int a = 0; a < 4; ++a) {
                part[0][a]     += h0 * w0[a];  part[1][a]     += h1 * w0[a];
                part[0][a + 4] += h0 * w1[a];  part[1][a + 4] += h1 * w1[a];
                part[0][a + 8] += h0 * w2v[a]; part[1][a + 8] += h1 * w2v[a];
            }
        }
    }
    // combine p pairs (lanes L, L^32 share q, differ in p low bit)
#pragma unroll
    for (int rr = 0; rr < 2; ++rr)
#pragma unroll
        for (int a = 0; a < ACT; ++a)
            part[rr][a] += __shfl_xor(part[rr][a], 32, 64);
    if (L < 32) {
#pragma unroll
        for (int rr = 0; rr < 2; ++rr)
#pragma unroll
            for (int a = 0; a < ACT; ++a) red[w][q][rr][a] = part[rr][a];
    }
    __syncthreads();

    if (t < 64) {
        const int m = m0 + t;
        const int qq = t >> 1, rr = t & 1;
        float lg[ACT];
#pragma unroll
        for (int a = 0; a < ACT; ++a)
            lg[a] = red[0][qq][rr][a] + red[1][qq][rr][a] + red[2][qq][rr][a] + red[3][qq][rr][a]
                  + b2[a];
        float mx = lg[0];
#pragma unroll
        for (int a = 1; a < ACT; ++a) mx = fmaxf(mx, lg[a]);
        float s = 0.f;
#pragma unroll
        for (int a = 0; a < ACT; ++a) { lg[a] = __expf(lg[a] - mx); s += lg[a]; }
        const float inv = 1.f / s;
        const int b = m >> 9, u = m & 511;
        const float msk = (u >= nr_flags[b] && u < nr_units[b]) ? 1.0f : 1e-9f;
        float* op = out0 + (size_t)m * ACT;
#pragma unroll
        for (int a = 0; a < ACT; ++a)
            op[a] = lg[a] * inv * msk;
    }
}

extern "C" void kernel_launch(void* const* d_in, const int* in_sizes, int n_in,
                              void* d_out, int out_size, void* d_ws, size_t ws_size,
                              hipStream_t stream) {
    const float* core   = (const float*)d_in[0];   // [64,1,512] f32
    const float* emb    = (const float*)d_in[1];   // [64,512,256] f32
    const int* nr_units = (const int*)d_in[2];     // [64,1] i32
    const int* nr_flags = (const int*)d_in[3];     // [64,1] i32
    const float* W1     = (const float*)d_in[4];   // [768,1024] f32
    const float* b1     = (const float*)d_in[5];   // [1024] f32
    const float* W2     = (const float*)d_in[6];   // [1024,12] f32
    const float* b2     = (const float*)d_in[7];   // [12] f32

    float* out0 = (float*)d_out;                       // probs [32768*12] f32
    float* out1 = out0 + (size_t)M_TOT * ACT;          // embedding [32768*1024] f32

    ushort_t* w1t = (ushort_t*)d_ws;                   // f16 [1024][256] = 512 KB
    float* cp = (float*)((char*)d_ws + (size_t)1024 * 256 * 2); // [64][1024] f32 = 256 KB

    transpose_k<<<dim3(4, 16), 256, 0, stream>>>(W1, w1t);
    corepart_k<<<dim3(4, 64), 256, 0, stream>>>(core, W1, b1, cp);
    gemm1_k<<<dim3(8, 256), 256, 0, stream>>>(emb, w1t, cp, out1);
    head_k<<<dim3(512), 256, 0, stream>>>(out1, W2, b2, nr_units, nr_flags, out0);
}

// Round 4
// 267.409 us; speedup vs baseline: 1.0732x; 1.0732x over previous
//
#include <hip/hip_runtime.h>
#include <hip/hip_fp16.h>
#include <cstdint>

typedef unsigned short ushort_t;
typedef _Float16 f16x8 __attribute__((ext_vector_type(8)));  // 8 f16 (4 VGPRs) for MFMA
typedef float f32x4 __attribute__((ext_vector_type(4)));

#define M_TOT  32768
#define K_EMB  256
#define K_CORE 512
#define ACT    12

__device__ __forceinline__ unsigned int pack2h(float a, float b) {
    __half2 h = __floats2half2_rn(a, b);
    union { __half2 h2; unsigned int u; } v; v.h2 = h; return v.u;
}

// ---------- kernel 1: transpose+convert W1[0:256, 0:1024] f32 -> W1T f16 [1024][256] ----------
__global__ __launch_bounds__(256) void transpose_k(const float* __restrict__ W1,
                                                   ushort_t* __restrict__ W1T) {
    __shared__ float tile[64][65];
    const int t = threadIdx.x;
    const int k0 = blockIdx.x * 64, n0 = blockIdx.y * 64;
    const int r = t >> 4, c4 = (t & 15) * 4;
#pragma unroll
    for (int p = 0; p < 4; ++p) {
        const int row = r + p * 16;
        const float4 v = *(const float4*)(W1 + (size_t)(k0 + row) * 1024 + n0 + c4);
        tile[row][c4 + 0] = v.x; tile[row][c4 + 1] = v.y;
        tile[row][c4 + 2] = v.z; tile[row][c4 + 3] = v.w;
    }
    __syncthreads();
#pragma unroll
    for (int p = 0; p < 4; ++p) {
        const int nrow = r + p * 16;
        uint2 o;
        o.x = pack2h(tile[c4 + 0][nrow], tile[c4 + 1][nrow]);
        o.y = pack2h(tile[c4 + 2][nrow], tile[c4 + 3][nrow]);
        *(uint2*)(W1T + (size_t)(n0 + nrow) * 256 + k0 + c4) = o;
    }
}

// ---------- kernel 2: cp[b][n] = b1[n] + sum_k core[b][k] * W1[256+k][n]  (exact f32) ----------
__global__ __launch_bounds__(256) void corepart_k(const float* __restrict__ core,
                                                  const float* __restrict__ W1,
                                                  const float* __restrict__ b1,
                                                  float* __restrict__ cp) {
    const int b = blockIdx.y;
    const int n = blockIdx.x * 256 + threadIdx.x;
    float s = b1[n];
    const float* cr = core + b * K_CORE;
    const float* wp = W1 + (size_t)K_EMB * 1024 + n;
#pragma unroll 8
    for (int k = 0; k < K_CORE; ++k)
        s += cr[k] * wp[(size_t)k * 1024];
    cp[b * 1024 + n] = s;
}

// ---------- kernel 3 (fused): per block = 128 m-rows, loop all 8 n-tiles.
// h = relu(emb@W1a + cp) -> out1 f32; logits accumulated in regs -> softmax -> out0.
// LDS 16B-group swizzle g ^= (row>>1)&3 breaks the 8-way frag-read conflict.
__global__ __launch_bounds__(256, 1) void fused_k(const float* __restrict__ emb,
                                                  const ushort_t* __restrict__ w1t,
                                                  const float* __restrict__ cp,
                                                  const float* __restrict__ W2,
                                                  const float* __restrict__ b2,
                                                  const int* __restrict__ nr_units,
                                                  const int* __restrict__ nr_flags,
                                                  float* __restrict__ out0,
                                                  float* __restrict__ out1) {
    __shared__ __align__(16) ushort_t Asl[128 * 32];
    __shared__ __align__(16) ushort_t Bsl[128 * 32];
    __shared__ __align__(16) float logitAcc[128][ACT];   // 6 KB

    const int t = threadIdx.x;
    const int w = t >> 6, L = t & 63;
    const int wm = w >> 1, wn = w & 1;
    const int lane16 = L & 15, qd = L >> 4;
    const int m0 = blockIdx.x * 128;
    const int bb = m0 >> 9;

    // ---- staging geometry: 512 chunks of 8 elems (row = c>>2, group g = c&3), swizzled LDS ----
    const int c0 = w * 128 + L, c1 = c0 + 64;
    const int rA0 = c0 >> 2, g0 = c0 & 3;
    const int rA1 = c1 >> 2, g1 = c1 & 3;
    uint4* lA0 = (uint4*)&Asl[rA0 * 32 + ((g0 ^ ((rA0 >> 1) & 3)) << 3)];
    uint4* lA1 = (uint4*)&Asl[rA1 * 32 + ((g1 ^ ((rA1 >> 1) & 3)) << 3)];
    uint4* lB0 = (uint4*)&Bsl[rA0 * 32 + ((g0 ^ ((rA0 >> 1) & 3)) << 3)];
    uint4* lB1 = (uint4*)&Bsl[rA1 * 32 + ((g1 ^ ((rA1 >> 1) & 3)) << 3)];
    const float*    gA0 = emb + (size_t)(m0 + rA0) * K_EMB + g0 * 8;
    const float*    gA1 = emb + (size_t)(m0 + rA1) * K_EMB + g1 * 8;
    const ushort_t* gB0 = w1t + (size_t)rA0 * K_EMB + g0 * 8;
    const ushort_t* gB1 = w1t + (size_t)rA1 * K_EMB + g1 * 8;

    // ---- fragment LDS offsets (swizzled), constant over loop ----
    int aoff[4], boff[4];
#pragma unroll
    for (int i = 0; i < 4; ++i) {
        const int ra = wm * 64 + i * 16 + lane16;
        aoff[i] = ra * 32 + ((qd ^ ((ra >> 1) & 3)) << 3);
        const int rb = wn * 64 + i * 16 + lane16;
        boff[i] = rb * 32 + ((qd ^ ((rb >> 1) & 3)) << 3);
    }

    // ---- accumulators ----
    f32x4 acc[4][4];
#pragma unroll
    for (int mi = 0; mi < 4; ++mi)
#pragma unroll
        for (int ni = 0; ni < 4; ++ni) acc[mi][ni] = (f32x4){0.f, 0.f, 0.f, 0.f};
    f32x4 la_a[16], la_b[16], la_c[16];   // per-lane logit partials: 16 rows x 12 acts
#pragma unroll
    for (int i = 0; i < 16; ++i) {
        la_a[i] = (f32x4){0.f, 0.f, 0.f, 0.f};
        la_b[i] = (f32x4){0.f, 0.f, 0.f, 0.f};
        la_c[i] = (f32x4){0.f, 0.f, 0.f, 0.f};
    }

    // ---- initial prefetch (it = 0: nt=0, ks=0) ----
    float4 pa0l = *(const float4*)gA0, pa0h = *(const float4*)(gA0 + 4);
    float4 pa1l = *(const float4*)gA1, pa1h = *(const float4*)(gA1 + 4);
    uint4  pb0  = *(const uint4*)gB0,  pb1  = *(const uint4*)gB1;

    for (int it = 0; it < 64; ++it) {
        if (it) __syncthreads();
        uint4 av0, av1;
        av0.x = pack2h(pa0l.x, pa0l.y); av0.y = pack2h(pa0l.z, pa0l.w);
        av0.z = pack2h(pa0h.x, pa0h.y); av0.w = pack2h(pa0h.z, pa0h.w);
        av1.x = pack2h(pa1l.x, pa1l.y); av1.y = pack2h(pa1l.z, pa1l.w);
        av1.z = pack2h(pa1h.x, pa1h.y); av1.w = pack2h(pa1h.z, pa1h.w);
        *lA0 = av0; *lA1 = av1; *lB0 = pb0; *lB1 = pb1;
        __syncthreads();
        if (it < 63) {
            const int itn = it + 1;
            const int ksn = itn & 7, ntn = itn >> 3;
            const size_t ao = (size_t)(ksn * 32);
            const size_t bo = (size_t)ntn * 128 * K_EMB + ksn * 32;
            pa0l = *(const float4*)(gA0 + ao); pa0h = *(const float4*)(gA0 + ao + 4);
            pa1l = *(const float4*)(gA1 + ao); pa1h = *(const float4*)(gA1 + ao + 4);
            pb0 = *(const uint4*)(gB0 + bo);   pb1 = *(const uint4*)(gB1 + bo);
        }
        f16x8 af[4], bfr[4];
#pragma unroll
        for (int mi = 0; mi < 4; ++mi) af[mi] = *(const f16x8*)&Asl[aoff[mi]];
#pragma unroll
        for (int ni = 0; ni < 4; ++ni) bfr[ni] = *(const f16x8*)&Bsl[boff[ni]];
#pragma unroll
        for (int mi = 0; mi < 4; ++mi)
#pragma unroll
            for (int ni = 0; ni < 4; ++ni)
                acc[mi][ni] = __builtin_amdgcn_mfma_f32_16x16x32_f16(af[mi], bfr[ni], acc[mi][ni], 0, 0, 0);

        if ((it & 7) == 7) {
            // ---- per-n-tile epilogue: bias+relu, store h, accumulate logit partials ----
            const int nt = it >> 3;
            const int colb = nt * 128 + wn * 64 + lane16;
            float cpv[4]; f32x4 w2a[4], w2b[4], w2c[4];
#pragma unroll
            for (int ni = 0; ni < 4; ++ni) {
                const int cg = colb + ni * 16;
                cpv[ni] = cp[bb * 1024 + cg];
                const f32x4* wp = (const f32x4*)(W2 + (size_t)cg * ACT);
                w2a[ni] = wp[0]; w2b[ni] = wp[1]; w2c[ni] = wp[2];
            }
#pragma unroll
            for (int mi = 0; mi < 4; ++mi) {
#pragma unroll
                for (int r = 0; r < 4; ++r) {
                    const size_t m = (size_t)(m0 + wm * 64 + mi * 16 + qd * 4 + r);
                    float* orow = out1 + m * 1024 + colb;
#pragma unroll
                    for (int ni = 0; ni < 4; ++ni) {
                        float v = acc[mi][ni][r] + cpv[ni];
                        v = v > 0.f ? v : 0.f;
                        orow[ni * 16] = v;
                        la_a[mi * 4 + r] += w2a[ni] * v;
                        la_b[mi * 4 + r] += w2b[ni] * v;
                        la_c[mi * 4 + r] += w2c[ni] * v;
                    }
                }
#pragma unroll
                for (int ni = 0; ni < 4; ++ni) acc[mi][ni] = (f32x4){0.f, 0.f, 0.f, 0.f};
            }
        }
    }

    // ---- reduce logit partials across lane16 (cols) within wave ----
#pragma unroll
    for (int i = 0; i < 16; ++i)
#pragma unroll
        for (int s = 1; s < 16; s <<= 1)
#pragma unroll
            for (int j = 0; j < 4; ++j) {
                la_a[i][j] += __shfl_xor(la_a[i][j], s, 64);
                la_b[i][j] += __shfl_xor(la_b[i][j], s, 64);
                la_c[i][j] += __shfl_xor(la_c[i][j], s, 64);
            }

    __syncthreads();   // Asl/Bsl done; now combine the two wn waves via LDS
    if (wn == 0 && lane16 == 0) {
#pragma unroll
        for (int i = 0; i < 16; ++i) {
            const int row = wm * 64 + (i >> 2) * 16 + qd * 4 + (i & 3);
            f32x4* p = (f32x4*)&logitAcc[row][0];
            p[0] = la_a[i]; p[1] = la_b[i]; p[2] = la_c[i];
        }
    }
    __syncthreads();
    if (wn == 1 && lane16 == 0) {
#pragma unroll
        for (int i = 0; i < 16; ++i) {
            const int row = wm * 64 + (i >> 2) * 16 + qd * 4 + (i & 3);
            f32x4* p = (f32x4*)&logitAcc[row][0];
            p[0] += la_a[i]; p[1] += la_b[i]; p[2] += la_c[i];
        }
    }
    __syncthreads();

    // ---- softmax + range mask, one thread per row ----
    if (t < 128) {
        float lg[ACT];
#pragma unroll
        for (int a = 0; a < ACT; ++a) lg[a] = logitAcc[t][a] + b2[a];
        float mx = lg[0];
#pragma unroll
        for (int a = 1; a < ACT; ++a) mx = fmaxf(mx, lg[a]);
        float s = 0.f;
#pragma unroll
        for (int a = 0; a < ACT; ++a) { lg[a] = __expf(lg[a] - mx); s += lg[a]; }
        const float inv = 1.f / s;
        const int m = m0 + t;
        const int u = m & 511;
        const float msk = (u >= nr_flags[bb] && u < nr_units[bb]) ? 1.0f : 1e-9f;
        f32x4* op = (f32x4*)(out0 + (size_t)m * ACT);
        f32x4 o0, o1, o2;
#pragma unroll
        for (int j = 0; j < 4; ++j) {
            o0[j] = lg[j] * inv * msk;
            o1[j] = lg[j + 4] * inv * msk;
            o2[j] = lg[j + 8] * inv * msk;
        }
        op[0] = o0; op[1] = o1; op[2] = o2;
    }
}

extern "C" void kernel_launch(void* const* d_in, const int* in_sizes, int n_in,
                              void* d_out, int out_size, void* d_ws, size_t ws_size,
                              hipStream_t stream) {
    const float* core   = (const float*)d_in[0];
    const float* emb    = (const float*)d_in[1];
    const int* nr_units = (const int*)d_in[2];
    const int* nr_flags = (const int*)d_in[3];
    const float* W1     = (const float*)d_in[4];
    const float* b1     = (const float*)d_in[5];
    const float* W2     = (const float*)d_in[6];
    const float* b2     = (const float*)d_in[7];

    float* out0 = (float*)d_out;                       // probs [32768*12] f32
    float* out1 = out0 + (size_t)M_TOT * ACT;          // embedding [32768*1024] f32

    ushort_t* w1t = (ushort_t*)d_ws;                   // f16 [1024][256] = 512 KB
    float* cp = (float*)((char*)d_ws + (size_t)1024 * 256 * 2); // [64][1024] f32

    transpose_k<<<dim3(4, 16), 256, 0, stream>>>(W1, w1t);
    corepart_k<<<dim3(4, 64), 256, 0, stream>>>(core, W1, b1, cp);
    fused_k<<<dim3(256), 256, 0, stream>>>(emb, w1t, cp, W2, b2, nr_units, nr_flags, out0, out1);
}